// Round 1
// baseline (2640.661 us; speedup 1.0000x reference)
//
#include <hip/hip_runtime.h>
#include <math.h>

#define PPRI 192
#define NB   32
#define NS   36
#define BP   6144   // NB*PPRI
#define NPIX 250
#define FPI  3.14159265358979323846f

// ---------------- init: pofm, prior234, proto_n, fc_w transpose ----------------
__global__ void k_init(float* __restrict__ pofm, float* __restrict__ p234,
                       float* __restrict__ protoN, float* __restrict__ fcT,
                       const float* __restrict__ fc_w, const float* __restrict__ protos) {
    int i = blockIdx.x * 256 + threadIdx.x;
    if (i < BP * NS) {
        int p = (i / NS) % PPRI;
        pofm[i] = ((float)p + 0.5f) / 192.0f;
    }
    if (i < BP) {
        p234[3*i+0] = 0.5f; p234[3*i+1] = 0.1f; p234[3*i+2] = 0.0f;
    }
    if (i < 2304 * 64) {
        int j = i >> 6, o = i & 63;
        fcT[i] = fc_w[o * 2304 + j];
    }
    if (i < 15) {
        float ss = 0.f;
        for (int c = 0; c < 64; ++c) { float v = protos[i*64+c]; ss += v*v; }
        float nrm = fmaxf(sqrtf(ss), 1e-12f);
        for (int c = 0; c < 64; ++c) protoN[i*64+c] = protos[i*64+c] / nrm;
    }
}

// ---------------- grid sample: pooled[bp][c][s] ----------------
__global__ void k_gridsample(const float* __restrict__ feat, int H, int W,
                             const float* __restrict__ pofm, float* __restrict__ pooled) {
    int t = blockIdx.x * 256 + threadIdx.x;
    if (t >= BP * NS) return;
    int bp = t / NS, s = t % NS;
    int b = bp / PPRI;
    float px = pofm[bp * NS + (NS - 1 - s)];
    px = fminf(fmaxf(px, -1e6f), 1e6f);            // clamps NaN too (fmaxf returns non-NaN)
    float pfy = (s == 0) ? 0.0f : ((float)(2*s+1) / 71.0f);
    float ix = px  * (float)(W - 1);
    float iy = pfy * (float)(H - 1);
    float x0f = floorf(ix), y0f = floorf(iy);
    float fx = ix - x0f, fy = iy - y0f;
    float vx0 = (x0f >= 0.f      && x0f      <= (float)(W-1)) ? 1.f : 0.f;
    float vx1 = (x0f+1.f >= 0.f  && x0f+1.f  <= (float)(W-1)) ? 1.f : 0.f;
    float vy0 = (y0f >= 0.f      && y0f      <= (float)(H-1)) ? 1.f : 0.f;
    float vy1 = (y0f+1.f >= 0.f  && y0f+1.f  <= (float)(H-1)) ? 1.f : 0.f;
    int x0 = min(max((int)x0f, 0), W-1);
    int x1 = min(max((int)x0f + 1, 0), W-1);
    int y0 = min(max((int)y0f, 0), H-1);
    int y1 = min(max((int)y0f + 1, 0), H-1);
    float w00 = (1.f-fx)*(1.f-fy)*vx0*vy0, w10 = fx*(1.f-fy)*vx1*vy0;
    float w01 = (1.f-fx)*fy*vx0*vy1,       w11 = fx*fy*vx1*vy1;
    int a00 = y0*W+x0, a10 = y0*W+x1, a01 = y1*W+x0, a11 = y1*W+x1;
    const float* fb = feat + (size_t)b * 64 * H * W;
    float* outp = pooled + (size_t)bp * 64 * NS + s;
    int hw = H * W;
    for (int c = 0; c < 64; ++c) {
        const float* f = fb + c * hw;
        outp[c * NS] = w00*f[a00] + w10*f[a10] + w01*f[a01] + w11*f[a11];
    }
}

// ---------------- rg conv1d: 64->48, k=9, pad=4, relu(scale*conv+bias) ----------------
__global__ __launch_bounds__(192) void k_rgconv(const float* __restrict__ x,
        const float* __restrict__ w, const float* __restrict__ scale,
        const float* __restrict__ bias, float* __restrict__ out) {
    __shared__ float xs[4][64][44];
    int tid = threadIdx.x;
    int bp0 = blockIdx.x * 4;
    for (int idx = tid; idx < 4*64*36; idx += 192) {
        int jj = idx / 2304, rem = idx % 2304;
        xs[jj][rem/36][4 + rem%36] = x[(size_t)(bp0+jj)*2304 + rem];
    }
    for (int idx = tid; idx < 4*64*8; idx += 192) {
        int jj = idx / 512, rem = idx % 512;
        int c = rem / 8, k = rem % 8;
        xs[jj][c][(k < 4) ? k : (36 + k)] = 0.f;
    }
    __syncthreads();
    int j = tid / 48, oc = tid % 48;
    float acc[36];
    #pragma unroll
    for (int s = 0; s < 36; ++s) acc[s] = 0.f;
    const float* wb = w + oc * 64 * 9;
    for (int ic = 0; ic < 64; ++ic) {
        float wv[9];
        #pragma unroll
        for (int k = 0; k < 9; ++k) wv[k] = wb[ic*9 + k];
        float xv[44];
        #pragma unroll
        for (int u = 0; u < 44; ++u) xv[u] = xs[j][ic][u];
        #pragma unroll
        for (int s = 0; s < 36; ++s) {
            #pragma unroll
            for (int k = 0; k < 9; ++k) acc[s] += wv[k] * xv[s+k];
        }
    }
    float sc = scale[oc], bi = bias[oc];
    float* ob = out + (size_t)(bp0+j) * 48 * 36 + oc * 36;
    #pragma unroll
    for (int s = 0; s < 36; ++s) ob[s] = fmaxf(acc[s]*sc + bi, 0.f);
}

// ---------------- cat conv1d: (48*nblk)->64, k=9, pad=4 ----------------
__global__ __launch_bounds__(128) void k_catconv(
        const float* __restrict__ rg0, const float* __restrict__ rg1, const float* __restrict__ rg2,
        int nblk, const float* __restrict__ w, const float* __restrict__ scale,
        const float* __restrict__ bias, float* __restrict__ out) {
    __shared__ float xs[2][144][44];
    int IC = nblk * 48;
    int tid = threadIdx.x;
    int bp0 = blockIdx.x * 2;
    for (int idx = tid; idx < 2*IC*36; idx += 128) {
        int jj = idx / (IC*36), rem = idx % (IC*36);
        int ch = rem / 36, s = rem % 36;
        const float* rp = (ch < 48) ? rg0 : ((ch < 96) ? rg1 : rg2);
        xs[jj][ch][4+s] = rp[(size_t)(bp0+jj)*1728 + (ch % 48)*36 + s];
    }
    for (int idx = tid; idx < 2*IC*8; idx += 128) {
        int jj = idx / (IC*8), rem = idx % (IC*8);
        int ch = rem / 8, k = rem % 8;
        xs[jj][ch][(k < 4) ? k : (36 + k)] = 0.f;
    }
    __syncthreads();
    int j = tid >> 6, oc = tid & 63;
    float acc[36];
    #pragma unroll
    for (int s = 0; s < 36; ++s) acc[s] = 0.f;
    const float* wb = w + (size_t)oc * IC * 9;
    for (int ic = 0; ic < IC; ++ic) {
        float wv[9];
        #pragma unroll
        for (int k = 0; k < 9; ++k) wv[k] = wb[ic*9 + k];
        float xv[44];
        #pragma unroll
        for (int u = 0; u < 44; ++u) xv[u] = xs[j][ic][u];
        #pragma unroll
        for (int s = 0; s < 36; ++s) {
            #pragma unroll
            for (int k = 0; k < 9; ++k) acc[s] += wv[k] * xv[s+k];
        }
    }
    float sc = scale[oc], bi = bias[oc];
    float* ob = out + (size_t)(bp0+j) * 2304 + oc * 36;
    #pragma unroll
    for (int s = 0; s < 36; ++s) ob[s] = fmaxf(acc[s]*sc + bi, 0.f);
}

// ---------------- fc(2304->64) + LayerNorm + relu ----------------
__global__ __launch_bounds__(256) void k_fc_ln(const float* __restrict__ x,
        const float* __restrict__ wT, const float* __restrict__ b,
        const float* __restrict__ gamma, const float* __restrict__ beta,
        float* __restrict__ roi) {
    __shared__ float xs[4][2304];
    int tid = threadIdx.x;
    int r0 = blockIdx.x * 4;
    for (int idx = tid; idx < 4*2304; idx += 256)
        xs[idx/2304][idx%2304] = x[(size_t)(r0 + idx/2304)*2304 + idx%2304];
    __syncthreads();
    int rr = tid >> 6, o = tid & 63;
    const float* xr = xs[rr];
    float acc = 0.f;
    #pragma unroll 8
    for (int j = 0; j < 2304; ++j) acc += xr[j] * wT[j*64 + o];
    float y = acc + b[o];
    float sum = y;
    #pragma unroll
    for (int off = 32; off > 0; off >>= 1) sum += __shfl_xor(sum, off);
    float mu = sum * (1.f/64.f);
    float d = y - mu;
    float vs = d * d;
    #pragma unroll
    for (int off = 32; off > 0; off >>= 1) vs += __shfl_xor(vs, off);
    float var = vs * (1.f/64.f);
    float outv = d * (1.0f / sqrtf(var + 1e-5f)) * gamma[o] + beta[o];
    roi[(size_t)(r0+rr)*64 + o] = fmaxf(outv, 0.f);
}

// ---------------- key/value maps at the 250 resize-nearest pixels ----------------
__global__ __launch_bounds__(64) void k_keyval(const float* __restrict__ feat, int H, int W,
        const float* __restrict__ kw, const float* __restrict__ ks, const float* __restrict__ kb,
        const float* __restrict__ vw, const float* __restrict__ vb,
        float* __restrict__ keymap, float* __restrict__ valmap) {
    int site = blockIdx.x;
    int b = site / NPIX, n = site % NPIX;
    int r = n / 25, q = n % 25;
    int y = r * H / 10, x = q * W / 25;
    __shared__ float xv[64];
    int tid = threadIdx.x;
    xv[tid] = feat[((size_t)(b*64 + tid) * H + y) * W + x];
    __syncthreads();
    float ak = 0.f, av = 0.f;
    #pragma unroll 8
    for (int c = 0; c < 64; ++c) {
        float f = xv[c];
        ak += f * kw[tid*64 + c];
        av += f * vw[tid*64 + c];
    }
    keymap[(size_t)(b*64 + tid) * NPIX + n] = fmaxf(ak * ks[tid] + kb[tid], 0.f);
    valmap[(size_t)(b*NPIX + n) * 64 + tid] = av + vb[tid];
}

// ---------------- attention (250 keys), roi updated in place ----------------
__global__ __launch_bounds__(256) void k_attn(float* __restrict__ roi,
        const float* __restrict__ keymap, const float* __restrict__ valmap,
        const float* __restrict__ fqw, const float* __restrict__ fqb,
        const float* __restrict__ aws, const float* __restrict__ awb) {
    int rI = blockIdx.x;
    int b = rI / PPRI, p = rI % PPRI;
    __shared__ float q[64];
    __shared__ float sc[256];
    __shared__ float red[4];
    int tid = threadIdx.x;
    if (tid < 64) q[tid] = fmaxf(roi[(size_t)rI*64 + tid] * fqw[p] + fqb[p], 0.f);
    __syncthreads();
    float s = -INFINITY;
    if (tid < NPIX) {
        float a = 0.f;
        const float* km = keymap + (size_t)b*64*NPIX + tid;
        #pragma unroll 8
        for (int c = 0; c < 64; ++c) a += q[c] * km[c*NPIX];
        s = a * 0.125f;
    }
    float m = s;
    #pragma unroll
    for (int off = 32; off > 0; off >>= 1) m = fmaxf(m, __shfl_xor(m, off));
    if ((tid & 63) == 0) red[tid >> 6] = m;
    __syncthreads();
    m = fmaxf(fmaxf(red[0], red[1]), fmaxf(red[2], red[3]));
    __syncthreads();
    float e = (tid < NPIX) ? expf(s - m) : 0.f;
    sc[tid] = e;
    float su = e;
    #pragma unroll
    for (int off = 32; off > 0; off >>= 1) su += __shfl_xor(su, off);
    if ((tid & 63) == 0) red[tid >> 6] = su;
    __syncthreads();
    su = red[0] + red[1] + red[2] + red[3];
    float inv = 1.f / su;
    if (tid < 64) {
        float acc = 0.f;
        const float* vm = valmap + (size_t)b*NPIX*64 + tid;
        for (int n = 0; n < NPIX; ++n) acc += sc[n] * vm[n*64];
        size_t o = (size_t)rI*64 + tid;
        roi[o] = roi[o] + (acc * inv) * aws[p] + awb[p];
    }
}

__device__ inline float dot64(const float* __restrict__ v, const float* __restrict__ w) {
    float a = 0.f;
    #pragma unroll 8
    for (int c = 0; c < 64; ++c) a += v[c] * w[c];
    return a;
}

// ---------------- heads: reg (+ cls at stage 2), geometry, prior update / output ----------------
__global__ __launch_bounds__(128) void k_head(int stage,
        float* __restrict__ p234g, float* __restrict__ pofm,
        const float* __restrict__ roi,
        const float* __restrict__ rw1, const float* __restrict__ rb1,
        const float* __restrict__ rw2, const float* __restrict__ rb2,
        const float* __restrict__ rhw, const float* __restrict__ rhb,
        const float* __restrict__ cw1, const float* __restrict__ cb1,
        const float* __restrict__ cw2, const float* __restrict__ cb2,
        const float* __restrict__ chw, const float* __restrict__ chb,
        float* __restrict__ out) {
    int rI = blockIdx.x;
    int b = rI / PPRI, p = rI % PPRI;
    int src = p * NB + b;                     // ff row scramble
    __shared__ float ff[64], h1[64], h2[64], rg[76];
    int tid = threadIdx.x;
    if (tid < 64) ff[tid] = roi[(size_t)src*64 + tid];
    __syncthreads();
    if (tid < 64) h1[tid] = fmaxf(dot64(ff, rw1 + tid*64) + rb1[tid], 0.f);
    __syncthreads();
    if (tid < 64) h2[tid] = fmaxf(dot64(h1, rw2 + tid*64) + rb2[tid], 0.f);
    __syncthreads();
    if (tid < 76) rg[tid] = dot64(h2, rhw + tid*64) + rhb[tid];
    __syncthreads();
    float* p234 = p234g + (size_t)rI * 3;
    float p2 = p234[0] + rg[0];
    float p3 = p234[1] + rg[1];
    float p4 = p234[2] + rg[2];
    float tanv = tanf(p4 * FPI + 1e-5f);
    if (stage < 2) {
        if (tid == 0) { p234[0] = p2; p234[1] = p3; p234[2] = p4; }
        if (tid < 36) {
            int k = (tid == 35) ? 71 : 2*tid;
            float prior_y = (float)(1.0 - (double)k / 71.0);
            float geom = (p3 * 799.0f + ((1.0f - prior_y - p2) * 320.0f) / tanv) / 799.0f;
            pofm[(size_t)rI * 36 + tid] = geom;
        }
    } else {
        if (tid < 64) h1[tid] = fmaxf(dot64(ff, cw1 + tid*64) + cb1[tid], 0.f);
        __syncthreads();
        if (tid < 64) h2[tid] = fmaxf(dot64(h1, cw2 + tid*64) + cb2[tid], 0.f);
        __syncthreads();
        float* ob = out + (size_t)rI * 78;
        if (tid < 2) ob[tid] = dot64(h2, chw + tid*64) + chb[tid];
        if (tid == 64) { ob[2] = p2; ob[3] = p3; ob[4] = p4; ob[5] = rg[3]; }
        if (tid < 72) {
            int k = tid;
            float prior_y = (float)(1.0 - (double)k / 71.0);
            float geom = (p3 * 799.0f + ((1.0f - prior_y - p2) * 320.0f) / tanv) / 799.0f;
            ob[6 + k] = geom + rg[4 + k];
        }
    }
}

// ---------------- final category + attribute heads ----------------
__global__ __launch_bounds__(64) void k_catattr(const float* __restrict__ roi,
        const float* __restrict__ cw1, const float* __restrict__ cb1,
        const float* __restrict__ cw2, const float* __restrict__ cb2,
        const float* __restrict__ protoN,
        const float* __restrict__ aw1, const float* __restrict__ ab1,
        const float* __restrict__ aw2, const float* __restrict__ ab2,
        const float* __restrict__ ahw, const float* __restrict__ ahb,
        float* __restrict__ out) {
    const size_t CAT_OFF = (size_t)BP * 78;
    const size_t ATTR_OFF = CAT_OFF + (size_t)BP * 15;
    int rI = blockIdx.x;
    int b = rI / PPRI, p = rI % PPRI;
    int src = p * NB + b;
    __shared__ float ff[64], h1[64], h2[64];
    int tid = threadIdx.x;
    ff[tid] = roi[(size_t)src*64 + tid];
    __syncthreads();
    h1[tid] = fmaxf(dot64(ff, cw1 + tid*64) + cb1[tid], 0.f);
    __syncthreads();
    float v = fmaxf(dot64(h1, cw2 + tid*64) + cb2[tid], 0.f);
    float ssq = v * v;
    #pragma unroll
    for (int off = 32; off > 0; off >>= 1) ssq += __shfl_xor(ssq, off);
    float nrm = fmaxf(sqrtf(ssq), 1e-12f);
    h2[tid] = v / nrm;
    __syncthreads();
    if (tid < 15) out[CAT_OFF + (size_t)rI*15 + tid] = dot64(h2, protoN + tid*64) * 20.0f;
    __syncthreads();   // everyone done reading h2/h1
    h1[tid] = fmaxf(dot64(ff, aw1 + tid*64) + ab1[tid], 0.f);
    __syncthreads();
    float va = fmaxf(dot64(h1, aw2 + tid*64) + ab2[tid], 0.f);
    h2[tid] = va;
    __syncthreads();
    if (tid < 4) out[ATTR_OFF + (size_t)rI*4 + tid] = dot64(h2, ahw + tid*64) + ahb[tid];
}

extern "C" void kernel_launch(void* const* d_in, const int* in_sizes, int n_in,
                              void* d_out, int out_size, void* d_ws, size_t ws_size,
                              hipStream_t stream) {
    (void)in_sizes; (void)n_in; (void)out_size; (void)ws_size;
    const float* feat_s8   = (const float*)d_in[0];
    const float* feat_s16  = (const float*)d_in[1];
    const float* feat_s32  = (const float*)d_in[2];
    const float* rg_conv_w     = (const float*)d_in[3];
    const float* rg_conv_scale = (const float*)d_in[4];
    const float* rg_conv_bias  = (const float*)d_in[5];
    const float* catconv_w[3]  = {(const float*)d_in[6], (const float*)d_in[7], (const float*)d_in[8]};
    const float* catconv_scale = (const float*)d_in[9];
    const float* catconv_bias  = (const float*)d_in[10];
    const float* fc_w = (const float*)d_in[11];
    const float* fc_b = (const float*)d_in[12];
    const float* ln_gamma = (const float*)d_in[13];
    const float* ln_beta  = (const float*)d_in[14];
    const float* fkey_w = (const float*)d_in[15];
    const float* fkey_scale = (const float*)d_in[16];
    const float* fkey_bias  = (const float*)d_in[17];
    const float* fvalue_w = (const float*)d_in[18];
    const float* fvalue_b = (const float*)d_in[19];
    const float* fquery_w = (const float*)d_in[20];
    const float* fquery_b = (const float*)d_in[21];
    const float* attn_w_scale = (const float*)d_in[22];
    const float* attn_w_bias  = (const float*)d_in[23];
    const float* cls_w1 = (const float*)d_in[24];
    const float* cls_b1 = (const float*)d_in[25];
    const float* cls_w2 = (const float*)d_in[26];
    const float* cls_b2 = (const float*)d_in[27];
    const float* reg_w1 = (const float*)d_in[28];
    const float* reg_b1 = (const float*)d_in[29];
    const float* reg_w2 = (const float*)d_in[30];
    const float* reg_b2 = (const float*)d_in[31];
    const float* cls_head_w = (const float*)d_in[32];
    const float* cls_head_b = (const float*)d_in[33];
    const float* reg_head_w = (const float*)d_in[34];
    const float* reg_head_b = (const float*)d_in[35];
    const float* cat_w1 = (const float*)d_in[36];
    const float* cat_b1 = (const float*)d_in[37];
    const float* cat_w2 = (const float*)d_in[38];
    const float* cat_b2 = (const float*)d_in[39];
    const float* prototypes = (const float*)d_in[40];
    const float* attr_w1 = (const float*)d_in[41];
    const float* attr_b1 = (const float*)d_in[42];
    const float* attr_w2 = (const float*)d_in[43];
    const float* attr_b2 = (const float*)d_in[44];
    const float* attr_head_w = (const float*)d_in[45];
    const float* attr_head_b = (const float*)d_in[46];

    float* ws = (float*)d_ws;
    // ws layout (floats)
    float* pofm   = ws;                       // 221184
    float* p234   = ws + 221184;              // 18432
    float* protoN = ws + 239616;              // 960
    float* fcT    = ws + 240576;              // 147456
    float* roi    = ws + 388032;              // 393216
    float* keymap = ws + 781248;              // 512000
    float* valmap = ws + 1293248;             // 512000
    float* bufPC  = ws + 1805248;             // 14155776 (pooled, then catconv out)
    float* rgf[3] = {ws + 15961024, ws + 26577856, ws + 37194688};  // 10616832 each

    float* out = (float*)d_out;

    k_init<<<864, 256, 0, stream>>>(pofm, p234, protoN, fcT, fc_w, prototypes);

    const float* feats[3] = {feat_s32, feat_s16, feat_s8};
    const int Hs[3] = {10, 20, 40}, Wstg[3] = {25, 50, 100};

    for (int st = 0; st < 3; ++st) {
        k_gridsample<<<864, 256, 0, stream>>>(feats[st], Hs[st], Wstg[st], pofm, bufPC);
        k_rgconv<<<1536, 192, 0, stream>>>(bufPC, rg_conv_w + st*48*64*9,
                                           rg_conv_scale + st*48, rg_conv_bias + st*48, rgf[st]);
        k_catconv<<<3072, 128, 0, stream>>>(rgf[0], rgf[1], rgf[2], st+1, catconv_w[st],
                                            catconv_scale + st*64, catconv_bias + st*64, bufPC);
        k_fc_ln<<<1536, 256, 0, stream>>>(bufPC, fcT, fc_b, ln_gamma, ln_beta, roi);
        k_keyval<<<NB*NPIX, 64, 0, stream>>>(feats[st], Hs[st], Wstg[st],
                                             fkey_w, fkey_scale, fkey_bias,
                                             fvalue_w, fvalue_b, keymap, valmap);
        k_attn<<<BP, 256, 0, stream>>>(roi, keymap, valmap, fquery_w, fquery_b,
                                       attn_w_scale, attn_w_bias);
        k_head<<<BP, 128, 0, stream>>>(st, p234, pofm, roi,
                                       reg_w1, reg_b1, reg_w2, reg_b2, reg_head_w, reg_head_b,
                                       cls_w1, cls_b1, cls_w2, cls_b2, cls_head_w, cls_head_b,
                                       out);
    }
    k_catattr<<<BP, 64, 0, stream>>>(roi, cat_w1, cat_b1, cat_w2, cat_b2, protoN,
                                     attr_w1, attr_b1, attr_w2, attr_b2,
                                     attr_head_w, attr_head_b, out);
}

// Round 3
// 2375.443 us; speedup vs baseline: 1.1116x; 1.1116x over previous
//
#include <hip/hip_runtime.h>
#include <math.h>

#define PPRI 192
#define NB   32
#define NS   36
#define BP   6144   // NB*PPRI
#define NPIX 250
#define FPI  3.14159265358979323846f

typedef short bf16x8 __attribute__((ext_vector_type(8)));
typedef float f32x4  __attribute__((ext_vector_type(4)));

__device__ inline short f2bf(float x) {
    union { float f; unsigned u; } v; v.f = x;
    unsigned r = v.u + 0x7fffu + ((v.u >> 16) & 1u);
    return (short)(r >> 16);
}
__device__ inline float bf2f(short s) {
    union { unsigned u; float f; } v; v.u = ((unsigned)(unsigned short)s) << 16; return v.f;
}
__device__ inline void splitbf(float x, short& h, short& l) {
    h = f2bf(x);
    l = f2bf(x - bf2f(h));
}

// ---------------- init: pofm, p234, protoN, fcT (s-major), hi/lo bf16 weights ----------------
__global__ void k_init(float* __restrict__ pofm, float* __restrict__ p234,
                       float* __restrict__ protoN, float* __restrict__ fcT,
                       const float* __restrict__ fc_w, const float* __restrict__ protos,
                       short* __restrict__ rgWh, short* __restrict__ rgWl,
                       const float* __restrict__ rg_w,
                       short* __restrict__ catWh, short* __restrict__ catWl,
                       const float* __restrict__ cw0, const float* __restrict__ cw1,
                       const float* __restrict__ cw2) {
    int i = blockIdx.x * 256 + threadIdx.x;
    if (i < BP * NS) {
        int p = (i / NS) % PPRI;
        pofm[i] = ((float)p + 0.5f) / 192.0f;
    }
    if (i < BP) {
        p234[3*i+0] = 0.5f; p234[3*i+1] = 0.1f; p234[3*i+2] = 0.0f;
    }
    if (i < 2304 * 64) {           // fcT[(s*64+oc)*64 + o] = fc_w[o][oc*36+s]
        int j = i >> 6, o = i & 63;
        int s = j >> 6, oc = j & 63;
        fcT[i] = fc_w[o * 2304 + oc * 36 + s];
    }
    if (i < 15) {
        float ss = 0.f;
        for (int c = 0; c < 64; ++c) { float v = protos[i*64+c]; ss += v*v; }
        float nrm = fmaxf(sqrtf(ss), 1e-12f);
        for (int c = 0; c < 64; ++c) protoN[i*64+c] = protos[i*64+c] / nrm;
    }
    if (i < 82944) {               // rgW[st][k][oc][ic] <- rg_w[st][oc][ic][k]
        int st = i / 27648, r = i % 27648;
        int k = r / 3072, r2 = r % 3072;
        int oc = r2 / 64, ic = r2 & 63;
        short h, l; splitbf(rg_w[((st*48 + oc)*64 + ic)*9 + k], h, l);
        rgWh[i] = h; rgWl[i] = l;
    }
    if (i < 184320) {              // catW[st][k][oc][icp], icw = {64,96,160}
        int st, base, icw; const float* w;
        if (i < 36864)      { st = 0; base = 0;     icw = 64;  w = cw0; }
        else if (i < 92160) { st = 1; base = 36864; icw = 96;  w = cw1; }
        else                { st = 2; base = 92160; icw = 160; w = cw2; }
        int r = i - base;
        int k = r / (64*icw), r2 = r % (64*icw);
        int oc = r2 / icw, icp = r2 % icw;
        int IC = 48 * (st + 1);
        float wv = (icp < IC) ? w[(oc*IC + icp)*9 + k] : 0.f;
        short h, l; splitbf(wv, h, l);
        catWh[i] = h; catWl[i] = l;
    }
}

// zero pos-pads (all 160 cols) and col-pad 144-159 of rgf hi/lo
__global__ __launch_bounds__(256) void k_zero_rgf(short* __restrict__ hi, short* __restrict__ lo) {
    int row = blockIdx.x;
    size_t base = (size_t)row * 44 * 160;
    for (int idx = threadIdx.x; idx < 44*160; idx += 256) {
        int pos = idx / 160, c = idx % 160;
        if (pos < 4 || pos >= 40 || c >= 144) { hi[base+idx] = 0; lo[base+idx] = 0; }
    }
}

// ---------------- grid sample -> pooled hi/lo bf16 [bp][44][64] ----------------
__global__ void k_gridsample(const float* __restrict__ feat, int H, int W,
                             const float* __restrict__ pofm,
                             short* __restrict__ pHi, short* __restrict__ pLo) {
    int t = blockIdx.x * 256 + threadIdx.x;
    if (t >= BP * NS) return;
    int bp = t / NS, s = t % NS;
    int b = bp / PPRI;
    size_t rb = (size_t)bp * 44 * 64;
    if (s < 8) {
        int pp = (s < 4) ? s : s + 36;
        bf16x8 z = {};
        for (int c0 = 0; c0 < 64; c0 += 8) {
            *(bf16x8*)(pHi + rb + pp*64 + c0) = z;
            *(bf16x8*)(pLo + rb + pp*64 + c0) = z;
        }
    }
    float px = pofm[bp * NS + (NS - 1 - s)];
    px = fminf(fmaxf(px, -1e6f), 1e6f);
    float pfy = (s == 0) ? 0.0f : ((float)(2*s+1) / 71.0f);
    float ix = px  * (float)(W - 1);
    float iy = pfy * (float)(H - 1);
    float x0f = floorf(ix), y0f = floorf(iy);
    float fx = ix - x0f, fy = iy - y0f;
    float vx0 = (x0f >= 0.f     && x0f     <= (float)(W-1)) ? 1.f : 0.f;
    float vx1 = (x0f+1.f >= 0.f && x0f+1.f <= (float)(W-1)) ? 1.f : 0.f;
    float vy0 = (y0f >= 0.f     && y0f     <= (float)(H-1)) ? 1.f : 0.f;
    float vy1 = (y0f+1.f >= 0.f && y0f+1.f <= (float)(H-1)) ? 1.f : 0.f;
    int x0 = min(max((int)x0f, 0), W-1);
    int x1 = min(max((int)x0f + 1, 0), W-1);
    int y0 = min(max((int)y0f, 0), H-1);
    int y1 = min(max((int)y0f + 1, 0), H-1);
    float w00 = (1.f-fx)*(1.f-fy)*vx0*vy0, w10 = fx*(1.f-fy)*vx1*vy0;
    float w01 = (1.f-fx)*fy*vx0*vy1,       w11 = fx*fy*vx1*vy1;
    int a00 = y0*W+x0, a10 = y0*W+x1, a01 = y1*W+x0, a11 = y1*W+x1;
    const float* fb = feat + (size_t)b * 64 * H * W;
    int hw = H * W;
    for (int c0 = 0; c0 < 64; c0 += 8) {
        bf16x8 ph, pl;
        #pragma unroll
        for (int c = 0; c < 8; ++c) {
            const float* f = fb + (c0 + c) * hw;
            float v = w00*f[a00] + w10*f[a10] + w01*f[a01] + w11*f[a11];
            short h, l; splitbf(v, h, l);
            ph[c] = h; pl[c] = l;
        }
        *(bf16x8*)(pHi + rb + (4+s)*64 + c0) = ph;
        *(bf16x8*)(pLo + rb + (4+s)*64 + c0) = pl;
    }
}

// ---------------- rg conv1d via split MFMA: pooled -> rgf[row][44][160] @ic_off ----------------
__global__ __launch_bounds__(256) void k_rgconv_mfma(
        const short* __restrict__ Xh, const short* __restrict__ Xl,
        const short* __restrict__ Wh, const short* __restrict__ Wl,
        const float* __restrict__ scale, const float* __restrict__ bias,
        short* __restrict__ outH, short* __restrict__ outL, int ic_off) {
    int wave = threadIdx.x >> 6, lane = threadIdx.x & 63;
    int row = blockIdx.x * 4 + wave;
    int lr = lane & 15, kg = lane >> 4;
    size_t rb = (size_t)row * 44 * 64;
    f32x4 acc[3][3] = {};
    for (int sh = 0; sh < 9; ++sh) {
        #pragma unroll
        for (int kc = 0; kc < 2; ++kc) {
            int icb = kc*32 + kg*8;
            int p0 = (lr + sh)*64 + icb, p1 = (16 + lr + sh)*64 + icb,
                p2 = min(32 + lr + sh, 43)*64 + icb;
            bf16x8 ah0 = *(const bf16x8*)(Xh + rb + p0);
            bf16x8 ah1 = *(const bf16x8*)(Xh + rb + p1);
            bf16x8 ah2 = *(const bf16x8*)(Xh + rb + p2);
            bf16x8 al0 = *(const bf16x8*)(Xl + rb + p0);
            bf16x8 al1 = *(const bf16x8*)(Xl + rb + p1);
            bf16x8 al2 = *(const bf16x8*)(Xl + rb + p2);
            size_t wb = (size_t)(sh*48)*64 + icb;
            bf16x8 bh0 = *(const bf16x8*)(Wh + wb + (lr     )*64);
            bf16x8 bh1 = *(const bf16x8*)(Wh + wb + (16 + lr)*64);
            bf16x8 bh2 = *(const bf16x8*)(Wh + wb + (32 + lr)*64);
            bf16x8 bl0 = *(const bf16x8*)(Wl + wb + (lr     )*64);
            bf16x8 bl1 = *(const bf16x8*)(Wl + wb + (16 + lr)*64);
            bf16x8 bl2 = *(const bf16x8*)(Wl + wb + (32 + lr)*64);
            bf16x8 ah[3] = {ah0, ah1, ah2}, al[3] = {al0, al1, al2};
            bf16x8 bh[3] = {bh0, bh1, bh2}, bl[3] = {bl0, bl1, bl2};
            #pragma unroll
            for (int mt = 0; mt < 3; ++mt)
                #pragma unroll
                for (int nt = 0; nt < 3; ++nt) {
                    acc[mt][nt] = __builtin_amdgcn_mfma_f32_16x16x32_bf16(ah[mt], bh[nt], acc[mt][nt], 0,0,0);
                    acc[mt][nt] = __builtin_amdgcn_mfma_f32_16x16x32_bf16(ah[mt], bl[nt], acc[mt][nt], 0,0,0);
                    acc[mt][nt] = __builtin_amdgcn_mfma_f32_16x16x32_bf16(al[mt], bh[nt], acc[mt][nt], 0,0,0);
                }
        }
    }
    size_t ob = (size_t)row * 44 * 160 + ic_off;
    #pragma unroll
    for (int nt = 0; nt < 3; ++nt) {
        int oc = nt*16 + lr;
        float sc = scale[oc], bi = bias[oc];
        #pragma unroll
        for (int mt = 0; mt < 3; ++mt) {
            #pragma unroll
            for (int i = 0; i < 4; ++i) {
                int s = mt*16 + kg*4 + i;
                if (s < 36) {
                    float v = fmaxf(acc[mt][nt][i]*sc + bi, 0.f);
                    short h, l; splitbf(v, h, l);
                    outH[ob + (4+s)*160 + oc] = h;
                    outL[ob + (4+s)*160 + oc] = l;
                }
            }
        }
    }
}

// ---------------- cat conv1d via split MFMA: rgf[row][44][160] -> catOut fp32 [row][36][64] ----------------
__global__ __launch_bounds__(256) void k_catconv_mfma(
        const short* __restrict__ Xh, const short* __restrict__ Xl,
        const short* __restrict__ Wh, const short* __restrict__ Wl, int NC,
        const float* __restrict__ scale, const float* __restrict__ bias,
        float* __restrict__ out) {
    int wave = threadIdx.x >> 6, lane = threadIdx.x & 63;
    int row = blockIdx.x * 4 + wave;
    int lr = lane & 15, kg = lane >> 4;
    int icw = NC * 32;
    size_t rb = (size_t)row * 44 * 160;
    f32x4 acc[3][4] = {};
    for (int sh = 0; sh < 9; ++sh) {
        for (int kc = 0; kc < NC; ++kc) {
            int icb = kc*32 + kg*8;
            int p0 = (lr + sh)*160 + icb, p1 = (16 + lr + sh)*160 + icb,
                p2 = min(32 + lr + sh, 43)*160 + icb;
            bf16x8 ah0 = *(const bf16x8*)(Xh + rb + p0);
            bf16x8 ah1 = *(const bf16x8*)(Xh + rb + p1);
            bf16x8 ah2 = *(const bf16x8*)(Xh + rb + p2);
            bf16x8 al0 = *(const bf16x8*)(Xl + rb + p0);
            bf16x8 al1 = *(const bf16x8*)(Xl + rb + p1);
            bf16x8 al2 = *(const bf16x8*)(Xl + rb + p2);
            size_t wb = (size_t)(sh*64)*icw + icb;
            bf16x8 ah[3] = {ah0, ah1, ah2}, al[3] = {al0, al1, al2};
            #pragma unroll
            for (int nt = 0; nt < 4; ++nt) {
                bf16x8 bh = *(const bf16x8*)(Wh + wb + (nt*16 + lr)*icw);
                bf16x8 bl = *(const bf16x8*)(Wl + wb + (nt*16 + lr)*icw);
                #pragma unroll
                for (int mt = 0; mt < 3; ++mt) {
                    acc[mt][nt] = __builtin_amdgcn_mfma_f32_16x16x32_bf16(ah[mt], bh, acc[mt][nt], 0,0,0);
                    acc[mt][nt] = __builtin_amdgcn_mfma_f32_16x16x32_bf16(ah[mt], bl, acc[mt][nt], 0,0,0);
                    acc[mt][nt] = __builtin_amdgcn_mfma_f32_16x16x32_bf16(al[mt], bh, acc[mt][nt], 0,0,0);
                }
            }
        }
    }
    float* orow = out + (size_t)row * 2304;
    #pragma unroll
    for (int nt = 0; nt < 4; ++nt) {
        int oc = nt*16 + lr;
        float sc = scale[oc], bi = bias[oc];
        #pragma unroll
        for (int mt = 0; mt < 3; ++mt) {
            #pragma unroll
            for (int i = 0; i < 4; ++i) {
                int s = mt*16 + kg*4 + i;
                if (s < 36)
                    orow[s*64 + oc] = fmaxf(acc[mt][nt][i]*sc + bi, 0.f);
            }
        }
    }
}

// ---------------- fc(2304->64) + LayerNorm + relu (fp32, s-major input & fcT) ----------------
__global__ __launch_bounds__(256) void k_fc_ln(const float* __restrict__ x,
        const float* __restrict__ wT, const float* __restrict__ b,
        const float* __restrict__ gamma, const float* __restrict__ beta,
        float* __restrict__ roi) {
    __shared__ float xs[4][2304];
    int tid = threadIdx.x;
    int r0 = blockIdx.x * 4;
    for (int idx = tid; idx < 4*2304; idx += 256)
        xs[idx/2304][idx%2304] = x[(size_t)(r0 + idx/2304)*2304 + idx%2304];
    __syncthreads();
    int rr = tid >> 6, o = tid & 63;
    const float* xr = xs[rr];
    float acc = 0.f;
    #pragma unroll 8
    for (int j = 0; j < 2304; ++j) acc += xr[j] * wT[j*64 + o];
    float y = acc + b[o];
    float sum = y;
    #pragma unroll
    for (int off = 32; off > 0; off >>= 1) sum += __shfl_xor(sum, off);
    float mu = sum * (1.f/64.f);
    float d = y - mu;
    float vs = d * d;
    #pragma unroll
    for (int off = 32; off > 0; off >>= 1) vs += __shfl_xor(vs, off);
    float var = vs * (1.f/64.f);
    float outv = d * (1.0f / sqrtf(var + 1e-5f)) * gamma[o] + beta[o];
    roi[(size_t)(r0+rr)*64 + o] = fmaxf(outv, 0.f);
}

// ---------------- key/value maps at the 250 resize-nearest pixels ----------------
__global__ __launch_bounds__(64) void k_keyval(const float* __restrict__ feat, int H, int W,
        const float* __restrict__ kw, const float* __restrict__ ks, const float* __restrict__ kb,
        const float* __restrict__ vw, const float* __restrict__ vb,
        float* __restrict__ keymap, float* __restrict__ valmap) {
    int site = blockIdx.x;
    int b = site / NPIX, n = site % NPIX;
    int r = n / 25, q = n % 25;
    int y = r * H / 10, x = q * W / 25;
    __shared__ float xv[64];
    int tid = threadIdx.x;
    xv[tid] = feat[((size_t)(b*64 + tid) * H + y) * W + x];
    __syncthreads();
    float ak = 0.f, av = 0.f;
    #pragma unroll 8
    for (int c = 0; c < 64; ++c) {
        float f = xv[c];
        ak += f * kw[tid*64 + c];
        av += f * vw[tid*64 + c];
    }
    keymap[(size_t)(b*64 + tid) * NPIX + n] = fmaxf(ak * ks[tid] + kb[tid], 0.f);
    valmap[(size_t)(b*NPIX + n) * 64 + tid] = av + vb[tid];
}

// ---------------- attention (250 keys), roi updated in place ----------------
__global__ __launch_bounds__(256) void k_attn(float* __restrict__ roi,
        const float* __restrict__ keymap, const float* __restrict__ valmap,
        const float* __restrict__ fqw, const float* __restrict__ fqb,
        const float* __restrict__ aws, const float* __restrict__ awb) {
    int rI = blockIdx.x;
    int b = rI / PPRI, p = rI % PPRI;
    __shared__ float q[64];
    __shared__ float sc[256];
    __shared__ float red[4];
    int tid = threadIdx.x;
    if (tid < 64) q[tid] = fmaxf(roi[(size_t)rI*64 + tid] * fqw[p] + fqb[p], 0.f);
    __syncthreads();
    float s = -INFINITY;
    if (tid < NPIX) {
        float a = 0.f;
        const float* km = keymap + (size_t)b*64*NPIX + tid;
        #pragma unroll 8
        for (int c = 0; c < 64; ++c) a += q[c] * km[c*NPIX];
        s = a * 0.125f;
    }
    float m = s;
    #pragma unroll
    for (int off = 32; off > 0; off >>= 1) m = fmaxf(m, __shfl_xor(m, off));
    if ((tid & 63) == 0) red[tid >> 6] = m;
    __syncthreads();
    m = fmaxf(fmaxf(red[0], red[1]), fmaxf(red[2], red[3]));
    __syncthreads();
    float e = (tid < NPIX) ? expf(s - m) : 0.f;
    sc[tid] = e;
    float su = e;
    #pragma unroll
    for (int off = 32; off > 0; off >>= 1) su += __shfl_xor(su, off);
    if ((tid & 63) == 0) red[tid >> 6] = su;
    __syncthreads();
    su = red[0] + red[1] + red[2] + red[3];
    float inv = 1.f / su;
    if (tid < 64) {
        float acc = 0.f;
        const float* vm = valmap + (size_t)b*NPIX*64 + tid;
        for (int n = 0; n < NPIX; ++n) acc += sc[n] * vm[n*64];
        size_t o = (size_t)rI*64 + tid;
        roi[o] = roi[o] + (acc * inv) * aws[p] + awb[p];
    }
}

__device__ inline float dot64(const float* __restrict__ v, const float* __restrict__ w) {
    float a = 0.f;
    #pragma unroll 8
    for (int c = 0; c < 64; ++c) a += v[c] * w[c];
    return a;
}

// ---------------- heads: reg (+ cls at stage 2), geometry, prior update / output ----------------
__global__ __launch_bounds__(128) void k_head(int stage,
        float* __restrict__ p234g, float* __restrict__ pofm,
        const float* __restrict__ roi,
        const float* __restrict__ rw1, const float* __restrict__ rb1,
        const float* __restrict__ rw2, const float* __restrict__ rb2,
        const float* __restrict__ rhw, const float* __restrict__ rhb,
        const float* __restrict__ cw1, const float* __restrict__ cb1,
        const float* __restrict__ cw2, const float* __restrict__ cb2,
        const float* __restrict__ chw, const float* __restrict__ chb,
        float* __restrict__ out) {
    int rI = blockIdx.x;
    int b = rI / PPRI, p = rI % PPRI;
    int src = p * NB + b;                     // ff row scramble
    __shared__ float ff[64], h1[64], h2[64], rg[76];
    int tid = threadIdx.x;
    if (tid < 64) ff[tid] = roi[(size_t)src*64 + tid];
    __syncthreads();
    if (tid < 64) h1[tid] = fmaxf(dot64(ff, rw1 + tid*64) + rb1[tid], 0.f);
    __syncthreads();
    if (tid < 64) h2[tid] = fmaxf(dot64(h1, rw2 + tid*64) + rb2[tid], 0.f);
    __syncthreads();
    if (tid < 76) rg[tid] = dot64(h2, rhw + tid*64) + rhb[tid];
    __syncthreads();
    float* p234 = p234g + (size_t)rI * 3;
    float p2 = p234[0] + rg[0];
    float p3 = p234[1] + rg[1];
    float p4 = p234[2] + rg[2];
    float tanv = tanf(p4 * FPI + 1e-5f);
    if (stage < 2) {
        if (tid == 0) { p234[0] = p2; p234[1] = p3; p234[2] = p4; }
        if (tid < 36) {
            int k = (tid == 35) ? 71 : 2*tid;
            float prior_y = (float)(1.0 - (double)k / 71.0);
            float geom = (p3 * 799.0f + ((1.0f - prior_y - p2) * 320.0f) / tanv) / 799.0f;
            pofm[(size_t)rI * 36 + tid] = geom;
        }
    } else {
        if (tid < 64) h1[tid] = fmaxf(dot64(ff, cw1 + tid*64) + cb1[tid], 0.f);
        __syncthreads();
        if (tid < 64) h2[tid] = fmaxf(dot64(h1, cw2 + tid*64) + cb2[tid], 0.f);
        __syncthreads();
        float* ob = out + (size_t)rI * 78;
        if (tid < 2) ob[tid] = dot64(h2, chw + tid*64) + chb[tid];
        if (tid == 64) { ob[2] = p2; ob[3] = p3; ob[4] = p4; ob[5] = rg[3]; }
        if (tid < 72) {
            int k = tid;
            float prior_y = (float)(1.0 - (double)k / 71.0);
            float geom = (p3 * 799.0f + ((1.0f - prior_y - p2) * 320.0f) / tanv) / 799.0f;
            ob[6 + k] = geom + rg[4 + k];
        }
    }
}

// ---------------- final category + attribute heads ----------------
__global__ __launch_bounds__(64) void k_catattr(const float* __restrict__ roi,
        const float* __restrict__ cw1, const float* __restrict__ cb1,
        const float* __restrict__ cw2, const float* __restrict__ cb2,
        const float* __restrict__ protoN,
        const float* __restrict__ aw1, const float* __restrict__ ab1,
        const float* __restrict__ aw2, const float* __restrict__ ab2,
        const float* __restrict__ ahw, const float* __restrict__ ahb,
        float* __restrict__ out) {
    const size_t CAT_OFF = (size_t)BP * 78;
    const size_t ATTR_OFF = CAT_OFF + (size_t)BP * 15;
    int rI = blockIdx.x;
    int b = rI / PPRI, p = rI % PPRI;
    int src = p * NB + b;
    __shared__ float ff[64], h1[64], h2[64];
    int tid = threadIdx.x;
    ff[tid] = roi[(size_t)src*64 + tid];
    __syncthreads();
    h1[tid] = fmaxf(dot64(ff, cw1 + tid*64) + cb1[tid], 0.f);
    __syncthreads();
    float v = fmaxf(dot64(h1, cw2 + tid*64) + cb2[tid], 0.f);
    float ssq = v * v;
    #pragma unroll
    for (int off = 32; off > 0; off >>= 1) ssq += __shfl_xor(ssq, off);
    float nrm = fmaxf(sqrtf(ssq), 1e-12f);
    h2[tid] = v / nrm;
    __syncthreads();
    if (tid < 15) out[CAT_OFF + (size_t)rI*15 + tid] = dot64(h2, protoN + tid*64) * 20.0f;
    __syncthreads();
    h1[tid] = fmaxf(dot64(ff, aw1 + tid*64) + ab1[tid], 0.f);
    __syncthreads();
    float va = fmaxf(dot64(h1, aw2 + tid*64) + ab2[tid], 0.f);
    h2[tid] = va;
    __syncthreads();
    if (tid < 4) out[ATTR_OFF + (size_t)rI*4 + tid] = dot64(h2, ahw + tid*64) + ahb[tid];
}

extern "C" void kernel_launch(void* const* d_in, const int* in_sizes, int n_in,
                              void* d_out, int out_size, void* d_ws, size_t ws_size,
                              hipStream_t stream) {
    (void)in_sizes; (void)n_in; (void)out_size; (void)ws_size;
    const float* feat_s8   = (const float*)d_in[0];
    const float* feat_s16  = (const float*)d_in[1];
    const float* feat_s32  = (const float*)d_in[2];
    const float* rg_conv_w     = (const float*)d_in[3];
    const float* rg_conv_scale = (const float*)d_in[4];
    const float* rg_conv_bias  = (const float*)d_in[5];
    const float* catconv_w[3]  = {(const float*)d_in[6], (const float*)d_in[7], (const float*)d_in[8]};
    const float* catconv_scale = (const float*)d_in[9];
    const float* catconv_bias  = (const float*)d_in[10];
    const float* fc_w = (const float*)d_in[11];
    const float* fc_b = (const float*)d_in[12];
    const float* ln_gamma = (const float*)d_in[13];
    const float* ln_beta  = (const float*)d_in[14];
    const float* fkey_w = (const float*)d_in[15];
    const float* fkey_scale = (const float*)d_in[16];
    const float* fkey_bias  = (const float*)d_in[17];
    const float* fvalue_w = (const float*)d_in[18];
    const float* fvalue_b = (const float*)d_in[19];
    const float* fquery_w = (const float*)d_in[20];
    const float* fquery_b = (const float*)d_in[21];
    const float* attn_w_scale = (const float*)d_in[22];
    const float* attn_w_bias  = (const float*)d_in[23];
    const float* cls_w1 = (const float*)d_in[24];
    const float* cls_b1 = (const float*)d_in[25];
    const float* cls_w2 = (const float*)d_in[26];
    const float* cls_b2 = (const float*)d_in[27];
    const float* reg_w1 = (const float*)d_in[28];
    const float* reg_b1 = (const float*)d_in[29];
    const float* reg_w2 = (const float*)d_in[30];
    const float* reg_b2 = (const float*)d_in[31];
    const float* cls_head_w = (const float*)d_in[32];
    const float* cls_head_b = (const float*)d_in[33];
    const float* reg_head_w = (const float*)d_in[34];
    const float* reg_head_b = (const float*)d_in[35];
    const float* cat_w1 = (const float*)d_in[36];
    const float* cat_b1 = (const float*)d_in[37];
    const float* cat_w2 = (const float*)d_in[38];
    const float* cat_b2 = (const float*)d_in[39];
    const float* prototypes = (const float*)d_in[40];
    const float* attr_w1 = (const float*)d_in[41];
    const float* attr_b1 = (const float*)d_in[42];
    const float* attr_w2 = (const float*)d_in[43];
    const float* attr_b2 = (const float*)d_in[44];
    const float* attr_head_w = (const float*)d_in[45];
    const float* attr_head_b = (const float*)d_in[46];

    float* ws = (float*)d_ws;
    // fp32 region (float offsets)
    float* pofm   = ws;                        // 221,184
    float* p234   = ws + 221184;               // 18,432
    float* protoN = ws + 239616;               // 960
    float* fcT    = ws + 240576;               // 147,456
    float* roi    = ws + 388032;               // 393,216
    float* keymap = ws + 781248;               // 512,000
    float* valmap = ws + 1293248;              // 512,000
    // UNION region (17,301,504 floats): catOut fp32 aliases pooled hi/lo (stage-serial liveness)
    float* catOut = ws + 1805248;              // 14,155,776 floats
    short* poolH  = (short*)(ws + 1805248);    // 17,301,504 shorts
    short* poolL  = (short*)(ws + 10456000);   // 17,301,504 shorts
    // rgf hi/lo: 6144*44*160 = 43,253,760 shorts each
    short* rgfH   = (short*)(ws + 19106752);
    short* rgfL   = (short*)(ws + 40733632);
    // weights
    short* rgWh   = (short*)(ws + 62360512);   // 82,944
    short* rgWl   = (short*)(ws + 62401984);   // 82,944
    short* catWh  = (short*)(ws + 62443456);   // 184,320
    short* catWl  = (short*)(ws + 62535616);   // 184,320

    float* out = (float*)d_out;

    k_init<<<864, 256, 0, stream>>>(pofm, p234, protoN, fcT, fc_w, prototypes,
                                    rgWh, rgWl, rg_conv_w, catWh, catWl,
                                    catconv_w[0], catconv_w[1], catconv_w[2]);
    k_zero_rgf<<<BP, 256, 0, stream>>>(rgfH, rgfL);

    const float* feats[3] = {feat_s32, feat_s16, feat_s8};
    const int Hs[3] = {10, 20, 40}, Wstg[3] = {25, 50, 100};
    const int catbase[3] = {0, 36864, 92160};
    const int catNC[3]   = {2, 3, 5};

    for (int st = 0; st < 3; ++st) {
        k_gridsample<<<864, 256, 0, stream>>>(feats[st], Hs[st], Wstg[st], pofm, poolH, poolL);
        k_rgconv_mfma<<<1536, 256, 0, stream>>>(poolH, poolL,
                                                rgWh + st*27648, rgWl + st*27648,
                                                rg_conv_scale + st*48, rg_conv_bias + st*48,
                                                rgfH, rgfL, st*48);
        k_catconv_mfma<<<1536, 256, 0, stream>>>(rgfH, rgfL,
                                                 catWh + catbase[st], catWl + catbase[st], catNC[st],
                                                 catconv_scale + st*64, catconv_bias + st*64,
                                                 catOut);
        k_fc_ln<<<1536, 256, 0, stream>>>(catOut, fcT, fc_b, ln_gamma, ln_beta, roi);
        k_keyval<<<NB*NPIX, 64, 0, stream>>>(feats[st], Hs[st], Wstg[st],
                                             fkey_w, fkey_scale, fkey_bias,
                                             fvalue_w, fvalue_b, keymap, valmap);
        k_attn<<<BP, 256, 0, stream>>>(roi, keymap, valmap, fquery_w, fquery_b,
                                       attn_w_scale, attn_w_bias);
        k_head<<<BP, 128, 0, stream>>>(st, p234, pofm, roi,
                                       reg_w1, reg_b1, reg_w2, reg_b2, reg_head_w, reg_head_b,
                                       cls_w1, cls_b1, cls_w2, cls_b2, cls_head_w, cls_head_b,
                                       out);
    }
    k_catattr<<<BP, 64, 0, stream>>>(roi, cat_w1, cat_b1, cat_w2, cat_b2, protoN,
                                     attr_w1, attr_b1, attr_w2, attr_b2,
                                     attr_head_w, attr_head_b, out);
}

// Round 4
// 1878.288 us; speedup vs baseline: 1.4059x; 1.2647x over previous
//
#include <hip/hip_runtime.h>
#include <math.h>

#define PPRI 192
#define NB   32
#define NS   36
#define BP   6144   // NB*PPRI
#define NPIX 250
#define FPI  3.14159265358979323846f

typedef short bf16x8 __attribute__((ext_vector_type(8)));
typedef float f32x4  __attribute__((ext_vector_type(4)));

__device__ inline short f2bf(float x) {
    union { float f; unsigned u; } v; v.f = x;
    unsigned r = v.u + 0x7fffu + ((v.u >> 16) & 1u);
    return (short)(r >> 16);
}
__device__ inline float bf2f(short s) {
    union { unsigned u; float f; } v; v.u = ((unsigned)(unsigned short)s) << 16; return v.f;
}
__device__ inline void splitbf(float x, short& h, short& l) {
    h = f2bf(x);
    l = f2bf(x - bf2f(h));
}

// ---------------- init: pofm, p234, protoN, fcWT hi/lo, conv weight hi/lo ----------------
__global__ void k_init(float* __restrict__ pofm, float* __restrict__ p234,
                       float* __restrict__ protoN,
                       short* __restrict__ fcWTh, short* __restrict__ fcWTl,
                       const float* __restrict__ fc_w, const float* __restrict__ protos,
                       short* __restrict__ rgWh, short* __restrict__ rgWl,
                       const float* __restrict__ rg_w,
                       short* __restrict__ catWh, short* __restrict__ catWl,
                       const float* __restrict__ cw0, const float* __restrict__ cw1,
                       const float* __restrict__ cw2) {
    int i = blockIdx.x * 256 + threadIdx.x;
    if (i < BP * NS) {
        int p = (i / NS) % PPRI;
        pofm[i] = ((float)p + 0.5f) / 192.0f;
    }
    if (i < BP) {
        p234[3*i+0] = 0.5f; p234[3*i+1] = 0.1f; p234[3*i+2] = 0.0f;
    }
    if (i < 64 * 2304) {           // fcWT[o][k], k = s*64+oc  <- fc_w[o][oc*36+s]
        int o = i / 2304, k = i % 2304;
        int s = k >> 6, oc = k & 63;
        short h, l; splitbf(fc_w[o * 2304 + oc * 36 + s], h, l);
        fcWTh[i] = h; fcWTl[i] = l;
    }
    if (i < 15) {
        float ss = 0.f;
        for (int c = 0; c < 64; ++c) { float v = protos[i*64+c]; ss += v*v; }
        float nrm = fmaxf(sqrtf(ss), 1e-12f);
        for (int c = 0; c < 64; ++c) protoN[i*64+c] = protos[i*64+c] / nrm;
    }
    if (i < 82944) {               // rgW[st][k][oc][ic] <- rg_w[st][oc][ic][k]
        int st = i / 27648, r = i % 27648;
        int k = r / 3072, r2 = r % 3072;
        int oc = r2 / 64, ic = r2 & 63;
        short h, l; splitbf(rg_w[((st*48 + oc)*64 + ic)*9 + k], h, l);
        rgWh[i] = h; rgWl[i] = l;
    }
    if (i < 184320) {              // catW[st][k][oc][icp], icw = {64,96,160}
        int st, base, icw; const float* w;
        if (i < 36864)      { st = 0; base = 0;     icw = 64;  w = cw0; }
        else if (i < 92160) { st = 1; base = 36864; icw = 96;  w = cw1; }
        else                { st = 2; base = 92160; icw = 160; w = cw2; }
        int r = i - base;
        int k = r / (64*icw), r2 = r % (64*icw);
        int oc = r2 / icw, icp = r2 % icw;
        int IC = 48 * (st + 1);
        float wv = (icp < IC) ? w[(oc*IC + icp)*9 + k] : 0.f;
        short h, l; splitbf(wv, h, l);
        catWh[i] = h; catWl[i] = l;
    }
}

// ---------------- grid sample -> pooled hi/lo bf16 compact [row][36][64] ----------------
__global__ void k_gridsample(const float* __restrict__ feat, int H, int W,
                             const float* __restrict__ pofm,
                             short* __restrict__ pHi, short* __restrict__ pLo) {
    int t = blockIdx.x * 256 + threadIdx.x;
    if (t >= BP * NS) return;
    int bp = t / NS, s = t % NS;
    int b = bp / PPRI;
    size_t rb = ((size_t)bp * 36 + s) * 64;
    float px = pofm[bp * NS + (NS - 1 - s)];
    px = fminf(fmaxf(px, -1e6f), 1e6f);
    float pfy = (s == 0) ? 0.0f : ((float)(2*s+1) / 71.0f);
    float ix = px  * (float)(W - 1);
    float iy = pfy * (float)(H - 1);
    float x0f = floorf(ix), y0f = floorf(iy);
    float fx = ix - x0f, fy = iy - y0f;
    float vx0 = (x0f >= 0.f     && x0f     <= (float)(W-1)) ? 1.f : 0.f;
    float vx1 = (x0f+1.f >= 0.f && x0f+1.f <= (float)(W-1)) ? 1.f : 0.f;
    float vy0 = (y0f >= 0.f     && y0f     <= (float)(H-1)) ? 1.f : 0.f;
    float vy1 = (y0f+1.f >= 0.f && y0f+1.f <= (float)(H-1)) ? 1.f : 0.f;
    int x0 = min(max((int)x0f, 0), W-1);
    int x1 = min(max((int)x0f + 1, 0), W-1);
    int y0 = min(max((int)y0f, 0), H-1);
    int y1 = min(max((int)y0f + 1, 0), H-1);
    float w00 = (1.f-fx)*(1.f-fy)*vx0*vy0, w10 = fx*(1.f-fy)*vx1*vy0;
    float w01 = (1.f-fx)*fy*vx0*vy1,       w11 = fx*fy*vx1*vy1;
    int a00 = y0*W+x0, a10 = y0*W+x1, a01 = y1*W+x0, a11 = y1*W+x1;
    const float* fb = feat + (size_t)b * 64 * H * W;
    int hw = H * W;
    for (int c0 = 0; c0 < 64; c0 += 8) {
        bf16x8 ph, pl;
        #pragma unroll
        for (int c = 0; c < 8; ++c) {
            const float* f = fb + (c0 + c) * hw;
            float v = w00*f[a00] + w10*f[a10] + w01*f[a01] + w11*f[a11];
            short h, l; splitbf(v, h, l);
            ph[c] = h; pl[c] = l;
        }
        *(bf16x8*)(pHi + rb + c0) = ph;
        *(bf16x8*)(pLo + rb + c0) = pl;
    }
}

// ---------------- rg conv1d, LDS-staged split MFMA: pooled -> rgfC[st] [row][36][48] hi/lo ----------------
// block: 256 thr (4 waves), 4 rows. LDS: [4 rows][hi|lo][44][72]
#define RGWP 72
__global__ __launch_bounds__(256) void k_rgconv_mfma(
        const short* __restrict__ Xh, const short* __restrict__ Xl,
        const short* __restrict__ Wh, const short* __restrict__ Wl,
        const float* __restrict__ scale, const float* __restrict__ bias,
        short* __restrict__ outH, short* __restrict__ outL) {
    __shared__ short sm[4 * 2 * 44 * RGWP];
    int tid = threadIdx.x;
    int row0 = blockIdx.x * 4;
    // stage: 44*9 chunks of 8 per row per array
    for (int idx = tid; idx < 4*44*(RGWP/8); idx += 256) {
        int rr = idx / (44*(RGWP/8)), rem = idx % (44*(RGWP/8));
        int pos = rem / (RGWP/8), c0 = (rem % (RGWP/8)) << 3;
        bf16x8 h = {}, l = {};
        if (pos >= 4 && pos < 40 && c0 < 64) {
            size_t src = ((size_t)(row0+rr)*36 + (pos-4))*64 + c0;
            h = *(const bf16x8*)(Xh + src);
            l = *(const bf16x8*)(Xl + src);
        }
        *(bf16x8*)(sm + (rr*2    )*44*RGWP + pos*RGWP + c0) = h;
        *(bf16x8*)(sm + (rr*2 + 1)*44*RGWP + pos*RGWP + c0) = l;
    }
    __syncthreads();
    int wave = tid >> 6, lane = tid & 63;
    int row = row0 + wave;
    int lr = lane & 15, kg = lane >> 4;
    const short* shb = sm + (wave*2    )*44*RGWP;
    const short* slb = sm + (wave*2 + 1)*44*RGWP;
    f32x4 acc[3][3] = {};
    for (int sh = 0; sh < 9; ++sh) {
        #pragma unroll
        for (int kc = 0; kc < 2; ++kc) {
            int icb = kc*32 + kg*8;
            int p0 = (lr + sh)*RGWP + icb, p1 = (16 + lr + sh)*RGWP + icb,
                p2 = (32 + lr + sh < 44 ? 32 + lr + sh : 43)*RGWP + icb;
            bf16x8 ah[3] = { *(const bf16x8*)(shb + p0), *(const bf16x8*)(shb + p1),
                             *(const bf16x8*)(shb + p2) };
            bf16x8 al[3] = { *(const bf16x8*)(slb + p0), *(const bf16x8*)(slb + p1),
                             *(const bf16x8*)(slb + p2) };
            size_t wb = (size_t)(sh*48)*64 + icb;
            #pragma unroll
            for (int nt = 0; nt < 3; ++nt) {
                bf16x8 bh = *(const bf16x8*)(Wh + wb + (nt*16 + lr)*64);
                bf16x8 bl = *(const bf16x8*)(Wl + wb + (nt*16 + lr)*64);
                #pragma unroll
                for (int mt = 0; mt < 3; ++mt) {
                    acc[mt][nt] = __builtin_amdgcn_mfma_f32_16x16x32_bf16(ah[mt], bh, acc[mt][nt], 0,0,0);
                    acc[mt][nt] = __builtin_amdgcn_mfma_f32_16x16x32_bf16(ah[mt], bl, acc[mt][nt], 0,0,0);
                    acc[mt][nt] = __builtin_amdgcn_mfma_f32_16x16x32_bf16(al[mt], bh, acc[mt][nt], 0,0,0);
                }
            }
        }
    }
    size_t ob = (size_t)row * 36 * 48;
    #pragma unroll
    for (int nt = 0; nt < 3; ++nt) {
        int oc = nt*16 + lr;
        float sc = scale[oc], bi = bias[oc];
        #pragma unroll
        for (int mt = 0; mt < 3; ++mt) {
            #pragma unroll
            for (int i = 0; i < 4; ++i) {
                int s = mt*16 + kg*4 + i;
                if (s < 36) {
                    float v = fmaxf(acc[mt][nt][i]*sc + bi, 0.f);
                    short h, l; splitbf(v, h, l);
                    outH[ob + s*48 + oc] = h;
                    outL[ob + s*48 + oc] = l;
                }
            }
        }
    }
}

// ---------------- cat conv1d, LDS-staged split MFMA -> catH hi/lo bf16 [row][36*64] ----------------
// dynamic LDS: [R rows][hi|lo][44][Wp]
__global__ void k_catconv_mfma(
        const short* __restrict__ rgCh, const short* __restrict__ rgCl,
        const short* __restrict__ Wh, const short* __restrict__ Wl,
        int NC, int ICr, int Wp, int R,
        const float* __restrict__ scale, const float* __restrict__ bias,
        short* __restrict__ outH, short* __restrict__ outL) {
    extern __shared__ short sm[];
    int tid = threadIdx.x;
    int nthr = R * 64;
    int row0 = blockIdx.x * R;
    int WpC = Wp >> 3;
    for (int idx = tid; idx < R*44*WpC; idx += nthr) {
        int rr = idx / (44*WpC), rem = idx % (44*WpC);
        int pos = rem / WpC, c0 = (rem % WpC) << 3;
        bf16x8 h = {}, l = {};
        if (pos >= 4 && pos < 40 && c0 < ICr) {
            int sidx = c0 / 48, cc = c0 % 48;
            size_t src = ((size_t)(sidx*BP + row0 + rr)*36 + (pos-4))*48 + cc;
            h = *(const bf16x8*)(rgCh + src);
            l = *(const bf16x8*)(rgCl + src);
        }
        *(bf16x8*)(sm + (rr*2    )*44*Wp + pos*Wp + c0) = h;
        *(bf16x8*)(sm + (rr*2 + 1)*44*Wp + pos*Wp + c0) = l;
    }
    __syncthreads();
    int wave = tid >> 6, lane = tid & 63;
    int row = row0 + wave;
    int lr = lane & 15, kg = lane >> 4;
    int icw = NC * 32;
    const short* shb = sm + (wave*2    )*44*Wp;
    const short* slb = sm + (wave*2 + 1)*44*Wp;
    f32x4 acc[3][4] = {};
    for (int sh = 0; sh < 9; ++sh) {
        for (int kc = 0; kc < NC; ++kc) {
            int icb = kc*32 + kg*8;
            int p0 = (lr + sh)*Wp + icb, p1 = (16 + lr + sh)*Wp + icb,
                p2 = (32 + lr + sh < 44 ? 32 + lr + sh : 43)*Wp + icb;
            bf16x8 ah[3] = { *(const bf16x8*)(shb + p0), *(const bf16x8*)(shb + p1),
                             *(const bf16x8*)(shb + p2) };
            bf16x8 al[3] = { *(const bf16x8*)(slb + p0), *(const bf16x8*)(slb + p1),
                             *(const bf16x8*)(slb + p2) };
            size_t wb = (size_t)(sh*64)*icw + icb;
            #pragma unroll
            for (int nt = 0; nt < 4; ++nt) {
                bf16x8 bh = *(const bf16x8*)(Wh + wb + (nt*16 + lr)*icw);
                bf16x8 bl = *(const bf16x8*)(Wl + wb + (nt*16 + lr)*icw);
                #pragma unroll
                for (int mt = 0; mt < 3; ++mt) {
                    acc[mt][nt] = __builtin_amdgcn_mfma_f32_16x16x32_bf16(ah[mt], bh, acc[mt][nt], 0,0,0);
                    acc[mt][nt] = __builtin_amdgcn_mfma_f32_16x16x32_bf16(ah[mt], bl, acc[mt][nt], 0,0,0);
                    acc[mt][nt] = __builtin_amdgcn_mfma_f32_16x16x32_bf16(al[mt], bh, acc[mt][nt], 0,0,0);
                }
            }
        }
    }
    short* oh = outH + (size_t)row * 2304;
    short* ol = outL + (size_t)row * 2304;
    #pragma unroll
    for (int nt = 0; nt < 4; ++nt) {
        int oc = nt*16 + lr;
        float sc = scale[oc], bi = bias[oc];
        #pragma unroll
        for (int mt = 0; mt < 3; ++mt) {
            #pragma unroll
            for (int i = 0; i < 4; ++i) {
                int s = mt*16 + kg*4 + i;
                if (s < 36) {
                    float v = fmaxf(acc[mt][nt][i]*sc + bi, 0.f);
                    short h, l; splitbf(v, h, l);
                    oh[s*64 + oc] = h;
                    ol[s*64 + oc] = l;
                }
            }
        }
    }
}

// ---------------- fc(2304->64) split MFMA + LayerNorm + relu ----------------
// grid 192, block 256 (4 waves = 4 N-tiles), 32 rows/block
__global__ __launch_bounds__(256) void k_fc_mfma(
        const short* __restrict__ Ah, const short* __restrict__ Al,
        const short* __restrict__ Bh, const short* __restrict__ Bl,
        const float* __restrict__ fcb,
        const float* __restrict__ gamma, const float* __restrict__ beta,
        float* __restrict__ roi) {
    __shared__ float lnb[32][64];
    int tid = threadIdx.x;
    int wave = tid >> 6, lane = tid & 63;
    int lr = lane & 15, kg = lane >> 4;
    int row0 = blockIdx.x * 32;
    const short* bhp = Bh + (size_t)(wave*16 + lr) * 2304;
    const short* blp = Bl + (size_t)(wave*16 + lr) * 2304;
    f32x4 acc[2] = {};
    for (int kk = 0; kk < 72; ++kk) {
        int k = kk*32 + kg*8;
        bf16x8 vbh = *(const bf16x8*)(bhp + k);
        bf16x8 vbl = *(const bf16x8*)(blp + k);
        #pragma unroll
        for (int mt = 0; mt < 2; ++mt) {
            size_t ar = (size_t)(row0 + mt*16 + lr) * 2304 + k;
            bf16x8 vah = *(const bf16x8*)(Ah + ar);
            bf16x8 val_ = *(const bf16x8*)(Al + ar);
            acc[mt] = __builtin_amdgcn_mfma_f32_16x16x32_bf16(vah, vbh, acc[mt], 0,0,0);
            acc[mt] = __builtin_amdgcn_mfma_f32_16x16x32_bf16(vah, vbl, acc[mt], 0,0,0);
            acc[mt] = __builtin_amdgcn_mfma_f32_16x16x32_bf16(val_, vbh, acc[mt], 0,0,0);
        }
    }
    #pragma unroll
    for (int mt = 0; mt < 2; ++mt)
        #pragma unroll
        for (int i = 0; i < 4; ++i)
            lnb[mt*16 + kg*4 + i][wave*16 + lr] = acc[mt][i];
    __syncthreads();
    int rr = tid >> 6, o = tid & 63;
    for (int rb = 0; rb < 8; ++rb) {
        int r = rb*4 + rr;
        float y = lnb[r][o] + fcb[o];
        float sum = y;
        #pragma unroll
        for (int off = 32; off > 0; off >>= 1) sum += __shfl_xor(sum, off);
        float mu = sum * (1.f/64.f);
        float d = y - mu;
        float vs = d * d;
        #pragma unroll
        for (int off = 32; off > 0; off >>= 1) vs += __shfl_xor(vs, off);
        float var = vs * (1.f/64.f);
        float outv = d * (1.0f / sqrtf(var + 1e-5f)) * gamma[o] + beta[o];
        roi[(size_t)(row0 + r)*64 + o] = fmaxf(outv, 0.f);
    }
}

// ---------------- key/value maps at the 250 resize-nearest pixels ----------------
__global__ __launch_bounds__(64) void k_keyval(const float* __restrict__ feat, int H, int W,
        const float* __restrict__ kw, const float* __restrict__ ks, const float* __restrict__ kb,
        const float* __restrict__ vw, const float* __restrict__ vb,
        float* __restrict__ keymap, float* __restrict__ valmap) {
    int site = blockIdx.x;
    int b = site / NPIX, n = site % NPIX;
    int r = n / 25, q = n % 25;
    int y = r * H / 10, x = q * W / 25;
    __shared__ float xv[64];
    int tid = threadIdx.x;
    xv[tid] = feat[((size_t)(b*64 + tid) * H + y) * W + x];
    __syncthreads();
    float ak = 0.f, av = 0.f;
    #pragma unroll 8
    for (int c = 0; c < 64; ++c) {
        float f = xv[c];
        ak += f * kw[tid*64 + c];
        av += f * vw[tid*64 + c];
    }
    keymap[(size_t)(b*64 + tid) * NPIX + n] = fmaxf(ak * ks[tid] + kb[tid], 0.f);
    valmap[(size_t)(b*NPIX + n) * 64 + tid] = av + vb[tid];
}

// ---------------- attention (250 keys), roi updated in place ----------------
__global__ __launch_bounds__(256) void k_attn(float* __restrict__ roi,
        const float* __restrict__ keymap, const float* __restrict__ valmap,
        const float* __restrict__ fqw, const float* __restrict__ fqb,
        const float* __restrict__ aws, const float* __restrict__ awb) {
    int rI = blockIdx.x;
    int b = rI / PPRI, p = rI % PPRI;
    __shared__ float q[64];
    __shared__ float sc[256];
    __shared__ float red[4];
    int tid = threadIdx.x;
    if (tid < 64) q[tid] = fmaxf(roi[(size_t)rI*64 + tid] * fqw[p] + fqb[p], 0.f);
    __syncthreads();
    float s = -INFINITY;
    if (tid < NPIX) {
        float a = 0.f;
        const float* km = keymap + (size_t)b*64*NPIX + tid;
        #pragma unroll 8
        for (int c = 0; c < 64; ++c) a += q[c] * km[c*NPIX];
        s = a * 0.125f;
    }
    float m = s;
    #pragma unroll
    for (int off = 32; off > 0; off >>= 1) m = fmaxf(m, __shfl_xor(m, off));
    if ((tid & 63) == 0) red[tid >> 6] = m;
    __syncthreads();
    m = fmaxf(fmaxf(red[0], red[1]), fmaxf(red[2], red[3]));
    __syncthreads();
    float e = (tid < NPIX) ? expf(s - m) : 0.f;
    sc[tid] = e;
    float su = e;
    #pragma unroll
    for (int off = 32; off > 0; off >>= 1) su += __shfl_xor(su, off);
    if ((tid & 63) == 0) red[tid >> 6] = su;
    __syncthreads();
    su = red[0] + red[1] + red[2] + red[3];
    float inv = 1.f / su;
    if (tid < 64) {
        float acc = 0.f;
        const float* vm = valmap + (size_t)b*NPIX*64 + tid;
        for (int n = 0; n < NPIX; ++n) acc += sc[n] * vm[n*64];
        size_t o = (size_t)rI*64 + tid;
        roi[o] = roi[o] + (acc * inv) * aws[p] + awb[p];
    }
}

__device__ inline float dot64(const float* __restrict__ v, const float* __restrict__ w) {
    float a = 0.f;
    #pragma unroll 8
    for (int c = 0; c < 64; ++c) a += v[c] * w[c];
    return a;
}

// ---------------- heads: reg (+ cls at stage 2), geometry, prior update / output ----------------
__global__ __launch_bounds__(128) void k_head(int stage,
        float* __restrict__ p234g, float* __restrict__ pofm,
        const float* __restrict__ roi,
        const float* __restrict__ rw1, const float* __restrict__ rb1,
        const float* __restrict__ rw2, const float* __restrict__ rb2,
        const float* __restrict__ rhw, const float* __restrict__ rhb,
        const float* __restrict__ cw1, const float* __restrict__ cb1,
        const float* __restrict__ cw2, const float* __restrict__ cb2,
        const float* __restrict__ chw, const float* __restrict__ chb,
        float* __restrict__ out) {
    int rI = blockIdx.x;
    int b = rI / PPRI, p = rI % PPRI;
    int src = p * NB + b;                     // ff row scramble
    __shared__ float ff[64], h1[64], h2[64], rg[76];
    int tid = threadIdx.x;
    if (tid < 64) ff[tid] = roi[(size_t)src*64 + tid];
    __syncthreads();
    if (tid < 64) h1[tid] = fmaxf(dot64(ff, rw1 + tid*64) + rb1[tid], 0.f);
    __syncthreads();
    if (tid < 64) h2[tid] = fmaxf(dot64(h1, rw2 + tid*64) + rb2[tid], 0.f);
    __syncthreads();
    if (tid < 76) rg[tid] = dot64(h2, rhw + tid*64) + rhb[tid];
    __syncthreads();
    float* p234 = p234g + (size_t)rI * 3;
    float p2 = p234[0] + rg[0];
    float p3 = p234[1] + rg[1];
    float p4 = p234[2] + rg[2];
    float tanv = tanf(p4 * FPI + 1e-5f);
    if (stage < 2) {
        if (tid == 0) { p234[0] = p2; p234[1] = p3; p234[2] = p4; }
        if (tid < 36) {
            int k = (tid == 35) ? 71 : 2*tid;
            float prior_y = (float)(1.0 - (double)k / 71.0);
            float geom = (p3 * 799.0f + ((1.0f - prior_y - p2) * 320.0f) / tanv) / 799.0f;
            pofm[(size_t)rI * 36 + tid] = geom;
        }
    } else {
        if (tid < 64) h1[tid] = fmaxf(dot64(ff, cw1 + tid*64) + cb1[tid], 0.f);
        __syncthreads();
        if (tid < 64) h2[tid] = fmaxf(dot64(h1, cw2 + tid*64) + cb2[tid], 0.f);
        __syncthreads();
        float* ob = out + (size_t)rI * 78;
        if (tid < 2) ob[tid] = dot64(h2, chw + tid*64) + chb[tid];
        if (tid == 64) { ob[2] = p2; ob[3] = p3; ob[4] = p4; ob[5] = rg[3]; }
        if (tid < 72) {
            int k = tid;
            float prior_y = (float)(1.0 - (double)k / 71.0);
            float geom = (p3 * 799.0f + ((1.0f - prior_y - p2) * 320.0f) / tanv) / 799.0f;
            ob[6 + k] = geom + rg[4 + k];
        }
    }
}

// ---------------- final category + attribute heads ----------------
__global__ __launch_bounds__(64) void k_catattr(const float* __restrict__ roi,
        const float* __restrict__ cw1, const float* __restrict__ cb1,
        const float* __restrict__ cw2, const float* __restrict__ cb2,
        const float* __restrict__ protoN,
        const float* __restrict__ aw1, const float* __restrict__ ab1,
        const float* __restrict__ aw2, const float* __restrict__ ab2,
        const float* __restrict__ ahw, const float* __restrict__ ahb,
        float* __restrict__ out) {
    const size_t CAT_OFF = (size_t)BP * 78;
    const size_t ATTR_OFF = CAT_OFF + (size_t)BP * 15;
    int rI = blockIdx.x;
    int b = rI / PPRI, p = rI % PPRI;
    int src = p * NB + b;
    __shared__ float ff[64], h1[64], h2[64];
    int tid = threadIdx.x;
    ff[tid] = roi[(size_t)src*64 + tid];
    __syncthreads();
    h1[tid] = fmaxf(dot64(ff, cw1 + tid*64) + cb1[tid], 0.f);
    __syncthreads();
    float v = fmaxf(dot64(h1, cw2 + tid*64) + cb2[tid], 0.f);
    float ssq = v * v;
    #pragma unroll
    for (int off = 32; off > 0; off >>= 1) ssq += __shfl_xor(ssq, off);
    float nrm = fmaxf(sqrtf(ssq), 1e-12f);
    h2[tid] = v / nrm;
    __syncthreads();
    if (tid < 15) out[CAT_OFF + (size_t)rI*15 + tid] = dot64(h2, protoN + tid*64) * 20.0f;
    __syncthreads();
    h1[tid] = fmaxf(dot64(ff, aw1 + tid*64) + ab1[tid], 0.f);
    __syncthreads();
    float va = fmaxf(dot64(h1, aw2 + tid*64) + ab2[tid], 0.f);
    h2[tid] = va;
    __syncthreads();
    if (tid < 4) out[ATTR_OFF + (size_t)rI*4 + tid] = dot64(h2, ahw + tid*64) + ahb[tid];
}

extern "C" void kernel_launch(void* const* d_in, const int* in_sizes, int n_in,
                              void* d_out, int out_size, void* d_ws, size_t ws_size,
                              hipStream_t stream) {
    (void)in_sizes; (void)n_in; (void)out_size; (void)ws_size;
    const float* feat_s8   = (const float*)d_in[0];
    const float* feat_s16  = (const float*)d_in[1];
    const float* feat_s32  = (const float*)d_in[2];
    const float* rg_conv_w     = (const float*)d_in[3];
    const float* rg_conv_scale = (const float*)d_in[4];
    const float* rg_conv_bias  = (const float*)d_in[5];
    const float* catconv_w[3]  = {(const float*)d_in[6], (const float*)d_in[7], (const float*)d_in[8]};
    const float* catconv_scale = (const float*)d_in[9];
    const float* catconv_bias  = (const float*)d_in[10];
    const float* fc_w = (const float*)d_in[11];
    const float* fc_b = (const float*)d_in[12];
    const float* ln_gamma = (const float*)d_in[13];
    const float* ln_beta  = (const float*)d_in[14];
    const float* fkey_w = (const float*)d_in[15];
    const float* fkey_scale = (const float*)d_in[16];
    const float* fkey_bias  = (const float*)d_in[17];
    const float* fvalue_w = (const float*)d_in[18];
    const float* fvalue_b = (const float*)d_in[19];
    const float* fquery_w = (const float*)d_in[20];
    const float* fquery_b = (const float*)d_in[21];
    const float* attn_w_scale = (const float*)d_in[22];
    const float* attn_w_bias  = (const float*)d_in[23];
    const float* cls_w1 = (const float*)d_in[24];
    const float* cls_b1 = (const float*)d_in[25];
    const float* cls_w2 = (const float*)d_in[26];
    const float* cls_b2 = (const float*)d_in[27];
    const float* reg_w1 = (const float*)d_in[28];
    const float* reg_b1 = (const float*)d_in[29];
    const float* reg_w2 = (const float*)d_in[30];
    const float* reg_b2 = (const float*)d_in[31];
    const float* cls_head_w = (const float*)d_in[32];
    const float* cls_head_b = (const float*)d_in[33];
    const float* reg_head_w = (const float*)d_in[34];
    const float* reg_head_b = (const float*)d_in[35];
    const float* cat_w1 = (const float*)d_in[36];
    const float* cat_b1 = (const float*)d_in[37];
    const float* cat_w2 = (const float*)d_in[38];
    const float* cat_b2 = (const float*)d_in[39];
    const float* prototypes = (const float*)d_in[40];
    const float* attr_w1 = (const float*)d_in[41];
    const float* attr_b1 = (const float*)d_in[42];
    const float* attr_w2 = (const float*)d_in[43];
    const float* attr_b2 = (const float*)d_in[44];
    const float* attr_head_w = (const float*)d_in[45];
    const float* attr_head_b = (const float*)d_in[46];

    float* ws = (float*)d_ws;
    // fp32 region (float offsets, all 16B-aligned)
    float* pofm   = ws;                        // 221,184
    float* p234   = ws + 221184;               // 18,432
    float* protoN = ws + 239616;               // 960
    float* roi    = ws + 240576;               // 393,216
    float* keymap = ws + 633792;               // 512,000
    float* valmap = ws + 1145792;              // 512,000
    // bf16 buffers (short*, offsets in floats)
    short* fcWTh  = (short*)(ws + 1657792);    // 147,456 sh
    short* fcWTl  = (short*)(ws + 1731520);    // 147,456 sh
    short* pooledH= (short*)(ws + 1805248);    // 14,155,776 sh
    short* pooledL= (short*)(ws + 8883136);    // 14,155,776 sh
    short* rgCh   = (short*)(ws + 15961024);   // 31,850,496 sh (3 stages)
    short* rgCl   = (short*)(ws + 31886272);   // 31,850,496 sh
    short* catHh  = (short*)(ws + 47811520);   // 14,155,776 sh
    short* catHl  = (short*)(ws + 54889408);   // 14,155,776 sh
    short* rgWh   = (short*)(ws + 61967296);   // 82,944 sh
    short* rgWl   = (short*)(ws + 62008768);   // 82,944 sh
    short* catWh  = (short*)(ws + 62050240);   // 184,320 sh
    short* catWl  = (short*)(ws + 62142400);   // 184,320 sh

    float* out = (float*)d_out;

    k_init<<<864, 256, 0, stream>>>(pofm, p234, protoN, fcWTh, fcWTl, fc_w, prototypes,
                                    rgWh, rgWl, rg_conv_w, catWh, catWl,
                                    catconv_w[0], catconv_w[1], catconv_w[2]);

    const float* feats[3] = {feat_s32, feat_s16, feat_s8};
    const int Hs[3] = {10, 20, 40}, Wstg[3] = {25, 50, 100};
    const int catbase[3] = {0, 36864, 92160};
    const int catNC[3]   = {2, 3, 5};
    const int catICr[3]  = {48, 96, 144};
    const int catWp[3]   = {72, 104, 168};
    const int catR[3]    = {4, 3, 2};

    for (int st = 0; st < 3; ++st) {
        k_gridsample<<<864, 256, 0, stream>>>(feats[st], Hs[st], Wstg[st], pofm,
                                              pooledH, pooledL);
        k_rgconv_mfma<<<1536, 256, 0, stream>>>(pooledH, pooledL,
                                                rgWh + st*27648, rgWl + st*27648,
                                                rg_conv_scale + st*48, rg_conv_bias + st*48,
                                                rgCh + (size_t)st*BP*1728,
                                                rgCl + (size_t)st*BP*1728);
        int ldsB = catR[st] * 2 * 44 * catWp[st] * 2;
        k_catconv_mfma<<<BP/catR[st], catR[st]*64, ldsB, stream>>>(
                rgCh, rgCl, catWh + catbase[st], catWl + catbase[st],
                catNC[st], catICr[st], catWp[st], catR[st],
                catconv_scale + st*64, catconv_bias + st*64, catHh, catHl);
        k_fc_mfma<<<192, 256, 0, stream>>>(catHh, catHl, fcWTh, fcWTl,
                                           fc_b, ln_gamma, ln_beta, roi);
        k_keyval<<<NB*NPIX, 64, 0, stream>>>(feats[st], Hs[st], Wstg[st],
                                             fkey_w, fkey_scale, fkey_bias,
                                             fvalue_w, fvalue_b, keymap, valmap);
        k_attn<<<BP, 256, 0, stream>>>(roi, keymap, valmap, fquery_w, fquery_b,
                                       attn_w_scale, attn_w_bias);
        k_head<<<BP, 128, 0, stream>>>(st, p234, pofm, roi,
                                       reg_w1, reg_b1, reg_w2, reg_b2, reg_head_w, reg_head_b,
                                       cls_w1, cls_b1, cls_w2, cls_b2, cls_head_w, cls_head_b,
                                       out);
    }
    k_catattr<<<BP, 64, 0, stream>>>(roi, cat_w1, cat_b1, cat_w2, cat_b2, protoN,
                                     attr_w1, attr_b1, attr_w2, attr_b2,
                                     attr_head_w, attr_head_b, out);
}